// Round 1
// baseline (6331.523 us; speedup 1.0000x reference)
//
#include <hip/hip_runtime.h>

typedef unsigned int uint;
typedef unsigned short ushort;

// MFMA fragment types (per guide: 16x16x32 bf16 -> 8 bf16 (as short8) in, 4 fp32 acc)
typedef short s8v __attribute__((ext_vector_type(8)));
typedef float f4v __attribute__((ext_vector_type(4)));

#define S_LEN 512
#define BATCH 64
#define DH    1024
#define DIN   1024

union B8 { s8v v; uint u[4]; unsigned long long ull[2]; ushort s[8]; };

__device__ inline ushort f2bf(float f){
  uint u = __builtin_bit_cast(uint, f);
  u += 0x7fffu + ((u >> 16) & 1u);
  return (ushort)(u >> 16);
}
__device__ inline float bf2f(ushort s){
  uint u = ((uint)s) << 16;
  return __builtin_bit_cast(float, u);
}

__device__ inline f4v mfma16(s8v a, s8v b, f4v c){
  return __builtin_amdgcn_mfma_f32_16x16x32_bf16(a, b, c, 0, 0, 0);
}

__device__ inline s8v ld_b8(const ushort* p){
  return *reinterpret_cast<const s8v*>(p);
}

// LLC-coherent (sc1) 16B fragment load as 2x8B relaxed agent atomics
__device__ inline s8v ld_b8_llc(const ushort* p){
  B8 b;
  const unsigned long long* q = (const unsigned long long*)p;
  b.ull[0] = __hip_atomic_load(q,   __ATOMIC_RELAXED, __HIP_MEMORY_SCOPE_AGENT);
  b.ull[1] = __hip_atomic_load(q+1, __ATOMIC_RELAXED, __HIP_MEMORY_SCOPE_AGENT);
  return b.v;
}

__device__ inline s8v cvt8(float4 a, float4 b){
  B8 r;
  r.s[0]=f2bf(a.x); r.s[1]=f2bf(a.y); r.s[2]=f2bf(a.z); r.s[3]=f2bf(a.w);
  r.s[4]=f2bf(b.x); r.s[5]=f2bf(b.y); r.s[6]=f2bf(b.z); r.s[7]=f2bf(b.w);
  return r.v;
}

// ---------------- fp32 -> bf16 conversion (weights) ----------------
__global__ void cvt_kernel(const float* __restrict__ src, ushort* __restrict__ dst, int n){
  int i = (blockIdx.x * blockDim.x + threadIdx.x) * 4;
  if (i + 3 < n){
    float4 v = *reinterpret_cast<const float4*>(src + i);
    unsigned long long p = (unsigned long long)f2bf(v.x)
                         | ((unsigned long long)f2bf(v.y) << 16)
                         | ((unsigned long long)f2bf(v.z) << 32)
                         | ((unsigned long long)f2bf(v.w) << 48);
    *reinterpret_cast<unsigned long long*>(dst + i) = p;
  }
}

// ---------------- input projections: xz/xr/xn = X @ W^T + b (bf16 out) ----------------
// grid (16, 256), block 256. m-tile 128 (4 waves x 32 rows), n-tile 64, 3 gates fused.
__global__ void __launch_bounds__(256, 1)
proj3_kernel(const float* __restrict__ X,
             const ushort* __restrict__ W0, const ushort* __restrict__ W1, const ushort* __restrict__ W2,
             const float* __restrict__ bias0, const float* __restrict__ bias1, const float* __restrict__ bias2,
             ushort* __restrict__ C0, ushort* __restrict__ C1, ushort* __restrict__ C2)
{
  const int lane = threadIdx.x & 63;
  const int wave = threadIdx.x >> 6;
  const int l15  = lane & 15;
  const int krow = (lane >> 4) << 3;
  const int n0 = blockIdx.x * 64;
  const int m0 = blockIdx.y * 128 + wave * 32;

  const ushort* Ws[3] = {W0, W1, W2};
  const float*  Bs[3] = {bias0, bias1, bias2};
  ushort*       Cs[3] = {C0, C1, C2};

  f4v acc[2][3][4];
  #pragma unroll
  for (int ms = 0; ms < 2; ++ms)
    #pragma unroll
    for (int g = 0; g < 3; ++g)
      #pragma unroll
      for (int nn = 0; nn < 4; ++nn)
        acc[ms][g][nn] = (f4v){0.f,0.f,0.f,0.f};

  const float* a0 = X + (m0 + l15) * DIN + krow;
  const float* a1 = a0 + 16 * DIN;

  for (int k = 0; k < DIN; k += 32){
    s8v af[2];
    {
      const float4* p0 = reinterpret_cast<const float4*>(a0 + k);
      const float4* p1 = reinterpret_cast<const float4*>(a1 + k);
      af[0] = cvt8(p0[0], p0[1]);
      af[1] = cvt8(p1[0], p1[1]);
    }
    #pragma unroll
    for (int g = 0; g < 3; ++g){
      const ushort* W = Ws[g];
      #pragma unroll
      for (int nn = 0; nn < 4; ++nn){
        s8v bfr = ld_b8(W + (n0 + nn*16 + l15) * DIN + k + krow);
        acc[0][g][nn] = mfma16(af[0], bfr, acc[0][g][nn]);
        acc[1][g][nn] = mfma16(af[1], bfr, acc[1][g][nn]);
      }
    }
  }

  #pragma unroll
  for (int g = 0; g < 3; ++g){
    ushort* C = Cs[g];
    #pragma unroll
    for (int nn = 0; nn < 4; ++nn){
      const int n = n0 + nn*16 + l15;
      const float bv = Bs[g][n];
      #pragma unroll
      for (int ms = 0; ms < 2; ++ms){
        #pragma unroll
        for (int r = 0; r < 4; ++r){
          int m = m0 + ms*16 + ((lane>>4)<<2) + r;
          C[m * DH + n] = f2bf(acc[ms][g][nn][r] + bv);
        }
      }
    }
  }
}

// ---------------- output projection: C = hs @ Why^T + b (fp32 out) ----------------
// grid (8, 256), block 256. m-tile 128, n-tile 128.
__global__ void __launch_bounds__(256, 1)
gemm1_kernel(const ushort* __restrict__ A, const ushort* __restrict__ W,
             const float* __restrict__ bias, float* __restrict__ C)
{
  const int lane = threadIdx.x & 63;
  const int wave = threadIdx.x >> 6;
  const int l15  = lane & 15;
  const int krow = (lane >> 4) << 3;
  const int n0 = blockIdx.x * 128;
  const int m0 = blockIdx.y * 128 + wave * 32;

  f4v acc[2][8];
  #pragma unroll
  for (int ms = 0; ms < 2; ++ms)
    #pragma unroll
    for (int nn = 0; nn < 8; ++nn)
      acc[ms][nn] = (f4v){0.f,0.f,0.f,0.f};

  const ushort* a0 = A + (m0 + l15) * DH + krow;
  const ushort* a1 = a0 + 16 * DH;

  for (int k = 0; k < DH; k += 32){
    s8v af0 = ld_b8(a0 + k);
    s8v af1 = ld_b8(a1 + k);
    #pragma unroll
    for (int nn = 0; nn < 8; ++nn){
      s8v b = ld_b8(W + (n0 + nn*16 + l15) * DH + k + krow);
      acc[0][nn] = mfma16(af0, b, acc[0][nn]);
      acc[1][nn] = mfma16(af1, b, acc[1][nn]);
    }
  }

  #pragma unroll
  for (int nn = 0; nn < 8; ++nn){
    const int n = n0 + nn*16 + l15;
    const float bv = bias[n];
    #pragma unroll
    for (int ms = 0; ms < 2; ++ms){
      #pragma unroll
      for (int r = 0; r < 4; ++r){
        int m = m0 + ms*16 + ((lane>>4)<<2) + r;
        C[m * DH + n] = acc[ms][nn][r] + bv;
      }
    }
  }
}

// ---------------- the GRU scan ----------------
// 256 wgs x 256 thr. wg = (group g = wid>>6 owning batches [16g,16g+16), j-tile jt = wid&63).
// 4 waves K-split (256 each). Recurrent weight fragments register-stationary.
// Double-buffered h/rh through LLC (sc1), monotone per-wg flags, per-wave polling.
__global__ void __launch_bounds__(256, 1)
scan_kernel(const ushort* __restrict__ xz, const ushort* __restrict__ xr,
            const ushort* __restrict__ xn,
            const ushort* __restrict__ Whz, const ushort* __restrict__ Whr,
            const ushort* __restrict__ Whn,
            const float* __restrict__ h0,
            ushort* __restrict__ hbuf,     // 2 x 64*1024
            ushort* __restrict__ rhbuf,    // 2 x 64*1024
            ushort* __restrict__ hs,       // 512*64*1024
            float*  __restrict__ hlast,    // 64*1024
            uint* __restrict__ hflags,     // 256 wgs * 4 uints
            uint* __restrict__ rhflags)
{
  const int tid  = threadIdx.x;
  const int wid  = blockIdx.x;
  const int g    = wid >> 6;
  const int jt   = wid & 63;
  const int b0   = g * 16;
  const int j0   = jt * 16;
  const int wave = tid >> 6;
  const int lane = tid & 63;
  const int l15  = lane & 15;
  const int krow = (lane >> 4) << 3;
  const int kbase = wave * 256;

  // stationary weight fragments: 24 x 4 VGPRs = 96 VGPRs
  s8v wz[8], wr[8], wn[8];
  {
    const int wrow = j0 + l15;
    #pragma unroll
    for (int kk = 0; kk < 8; ++kk){
      int off = wrow * DH + kbase + kk*32 + krow;
      wz[kk] = ld_b8(Whz + off);
      wr[kk] = ld_b8(Whr + off);
      wn[kk] = ld_b8(Whn + off);
    }
  }

  const int bl = tid >> 4;         // 0..15 local batch row
  const int jl = tid & 15;         // 0..15 local hidden col
  const int brow = b0 + bl;
  const int jcol = j0 + jl;
  const int arow = b0 + l15;       // MFMA A-operand row for this lane

  __shared__ float red[8][256];

  // init h_{-1} = h0 into hbuf[1]
  float h = h0[brow * DH + jcol];
  {
    ushort mybf = f2bf(h);
    uint other = (uint)(ushort)__shfl_xor((int)mybf, 1, 64);
    if ((tid & 1) == 0){
      uint pack = (uint)mybf | (other << 16);
      uint* dst = (uint*)(hbuf + 64*1024 + brow*DH + jcol);
      __hip_atomic_store(dst, pack, __ATOMIC_RELAXED, __HIP_MEMORY_SCOPE_AGENT);
    }
  }
  __syncthreads();   // drains vmcnt before flag publish
  if (tid == 0)
    __hip_atomic_store(&hflags[wid*4], 1u, __ATOMIC_RELAXED, __HIP_MEMORY_SCOPE_AGENT);

  float zreg = 0.f;

  #pragma unroll 1
  for (int t = 0; t < S_LEN; ++t){
    // ---- phase A: z, r ----
    {
      const uint* fp = hflags + (g*64 + wave*16 + l15) * 4;
      const uint tgt = (uint)(t + 1);
      while (true){
        uint v = __hip_atomic_load(fp, __ATOMIC_RELAXED, __HIP_MEMORY_SCOPE_AGENT);
        if (__all(v >= tgt)) break;
        __builtin_amdgcn_s_sleep(2);
      }
    }
    __asm__ volatile("" ::: "memory");

    const int xidx = (t * BATCH + brow) * DH + jcol;
    float xzv = bf2f(xz[xidx]);
    float xrv = bf2f(xr[xidx]);

    f4v accz = (f4v){0.f,0.f,0.f,0.f};
    f4v accr = (f4v){0.f,0.f,0.f,0.f};
    {
      const ushort* ap = hbuf + ((t ^ 1) & 1) * (64*1024) + arow * DH + kbase + krow;
      #pragma unroll
      for (int kk = 0; kk < 8; ++kk){
        s8v a = ld_b8_llc(ap + kk*32);
        accz = mfma16(a, wz[kk], accz);
        accr = mfma16(a, wr[kk], accr);
      }
    }
    {
      int base = ((lane >> 4) * 4) * 16 + l15;
      #pragma unroll
      for (int r = 0; r < 4; ++r){
        red[wave][base + r*16]   = accz[r];
        red[4+wave][base + r*16] = accr[r];
      }
    }
    __syncthreads();
    float sz = red[0][tid] + red[1][tid] + red[2][tid] + red[3][tid];
    float sr = red[4][tid] + red[5][tid] + red[6][tid] + red[7][tid];
    float z = 1.f / (1.f + __expf(-(xzv + sz)));
    float r = 1.f / (1.f + __expf(-(xrv + sr)));
    zreg = z;
    float rh = r * h;
    {
      ushort mybf = f2bf(rh);
      uint other = (uint)(ushort)__shfl_xor((int)mybf, 1, 64);
      if ((tid & 1) == 0){
        uint pack = (uint)mybf | (other << 16);
        uint* dst = (uint*)(rhbuf + (t & 1)*(64*1024) + brow*DH + jcol);
        __hip_atomic_store(dst, pack, __ATOMIC_RELAXED, __HIP_MEMORY_SCOPE_AGENT);
      }
    }
    __syncthreads();   // red reads done + rh stores drained
    if (tid == 0)
      __hip_atomic_store(&rhflags[wid*4], (uint)(t+1), __ATOMIC_RELAXED, __HIP_MEMORY_SCOPE_AGENT);

    // ---- phase B: n, h update ----
    {
      const uint* fp = rhflags + (g*64 + wave*16 + l15) * 4;
      const uint tgt = (uint)(t + 1);
      while (true){
        uint v = __hip_atomic_load(fp, __ATOMIC_RELAXED, __HIP_MEMORY_SCOPE_AGENT);
        if (__all(v >= tgt)) break;
        __builtin_amdgcn_s_sleep(2);
      }
    }
    __asm__ volatile("" ::: "memory");

    float xnv = bf2f(xn[xidx]);
    f4v accn = (f4v){0.f,0.f,0.f,0.f};
    {
      const ushort* ap = rhbuf + (t & 1)*(64*1024) + arow * DH + kbase + krow;
      #pragma unroll
      for (int kk = 0; kk < 8; ++kk){
        s8v a = ld_b8_llc(ap + kk*32);
        accn = mfma16(a, wn[kk], accn);
      }
    }
    {
      int base = ((lane >> 4) * 4) * 16 + l15;
      #pragma unroll
      for (int r4 = 0; r4 < 4; ++r4)
        red[wave][base + r4*16] = accn[r4];
    }
    __syncthreads();
    float sn = red[0][tid] + red[1][tid] + red[2][tid] + red[3][tid];
    float pre = xnv + sn;
    float e = __expf(2.f * pre);
    float n = 1.f - 2.f / (e + 1.f);
    float hnew = h + zreg * (n - h);
    h = hnew;
    {
      ushort mybf = f2bf(hnew);
      uint other = (uint)(ushort)__shfl_xor((int)mybf, 1, 64);
      if ((tid & 1) == 0){
        uint pack = (uint)mybf | (other << 16);
        uint* dst = (uint*)(hbuf + (t & 1)*(64*1024) + brow*DH + jcol);
        __hip_atomic_store(dst, pack, __ATOMIC_RELAXED, __HIP_MEMORY_SCOPE_AGENT);
      }
      hs[xidx] = mybf;                       // normal store; consumed next kernel
      if (t == S_LEN-1) hlast[brow*DH + jcol] = hnew;
    }
    __syncthreads();   // drains vmcnt
    if (tid == 0)
      __hip_atomic_store(&hflags[wid*4], (uint)(t+2), __ATOMIC_RELAXED, __HIP_MEMORY_SCOPE_AGENT);
  }
}

extern "C" void kernel_launch(void* const* d_in, const int* in_sizes, int n_in,
                              void* d_out, int out_size, void* d_ws, size_t ws_size,
                              hipStream_t stream) {
  const float* x_seq = (const float*)d_in[0];
  const float* h0    = (const float*)d_in[1];
  const float* Wxz_w = (const float*)d_in[2];
  const float* Wxz_b = (const float*)d_in[3];
  const float* Whz_w = (const float*)d_in[4];
  const float* Wxr_w = (const float*)d_in[5];
  const float* Wxr_b = (const float*)d_in[6];
  const float* Whr_w = (const float*)d_in[7];
  const float* Wxn_w = (const float*)d_in[8];
  const float* Wxn_b = (const float*)d_in[9];
  const float* Whn_w = (const float*)d_in[10];
  const float* Why_w = (const float*)d_in[11];
  const float* Why_b = (const float*)d_in[12];

  const size_t MiB = 1u << 20;
  unsigned char* ws = (unsigned char*)d_ws;

  ushort* Whz16 = (ushort*)(ws + 0*MiB);
  ushort* Whr16 = (ushort*)(ws + 2*MiB);
  ushort* Whn16 = (ushort*)(ws + 4*MiB);
  ushort* Wxz16 = (ushort*)(ws + 6*MiB);
  ushort* Wxr16 = (ushort*)(ws + 8*MiB);
  ushort* Wxn16 = (ushort*)(ws + 10*MiB);
  ushort* Why16 = (ushort*)(ws + 12*MiB);
  ushort* xn_buf = (ushort*)(ws + 16*MiB);          // 64 MiB
  ushort* hs     = (ushort*)(ws + 80*MiB);          // 64 MiB
  ushort* hbuf   = (ushort*)(ws + 144*MiB);         // 256 KiB (2 bufs)
  ushort* rhbuf  = (ushort*)(ws + 144*MiB + 256*1024);
  uint*   hflags = (uint*)  (ws + 144*MiB + 512*1024);
  uint*   rhflags= (uint*)  (ws + 144*MiB + 516*1024);

  // xz/xr live in d_out as bf16 scratch (overwritten by gemm1 later; h_last tail disjoint)
  ushort* xz_buf = (ushort*)d_out;                  // 64 MiB
  ushort* xr_buf = xz_buf + (size_t)S_LEN*BATCH*DH; // 64 MiB
  float*  out_f  = (float*)d_out;
  float*  hlast  = out_f + (size_t)S_LEN*BATCH*DH;

  const int NW = DH * DIN; // 1048576 elems per weight matrix

  cvt_kernel<<<1024, 256, 0, stream>>>(Whz_w, Whz16, NW);
  cvt_kernel<<<1024, 256, 0, stream>>>(Whr_w, Whr16, NW);
  cvt_kernel<<<1024, 256, 0, stream>>>(Whn_w, Whn16, NW);
  cvt_kernel<<<1024, 256, 0, stream>>>(Wxz_w, Wxz16, NW);
  cvt_kernel<<<1024, 256, 0, stream>>>(Wxr_w, Wxr16, NW);
  cvt_kernel<<<1024, 256, 0, stream>>>(Wxn_w, Wxn16, NW);
  cvt_kernel<<<1024, 256, 0, stream>>>(Why_w, Why16, NW);

  proj3_kernel<<<dim3(16, 256), 256, 0, stream>>>(
      x_seq, Wxz16, Wxr16, Wxn16, Wxz_b, Wxr_b, Wxn_b, xz_buf, xr_buf, xn_buf);

  hipMemsetAsync((void*)hflags, 0, 8192, stream);

  scan_kernel<<<256, 256, 0, stream>>>(
      xz_buf, xr_buf, xn_buf, Whz16, Whr16, Whn16, h0,
      hbuf, rhbuf, hs, hlast, hflags, rhflags);

  gemm1_kernel<<<dim3(8, 256), 256, 0, stream>>>(hs, Why16, Why_b, out_f);
}